// Round 18
// baseline (125.396 us; speedup 1.0000x reference)
//
#include <hip/hip_runtime.h>
#include <math.h>

typedef unsigned int u32;
typedef float vf2 __attribute__((ext_vector_type(2)));
typedef float f4v __attribute__((ext_vector_type(4)));

#define N_TOTAL 500000
#define P_NODES 21
#define KNEG    5
#define DDIM    128
#define BATCH   1024
#define N_PAIRS 185
#define N_NEG   (N_PAIRS * KNEG)            // 925
#define NNEG_TOT (N_PAIRS * BATCH * KNEG)   // 947200
#define C_ROWS  (BATCH * P_NODES)           // 21504

#define CONV_BLOCKS ((N_TOTAL * DDIM / 16) / 256)   // 15625
#define MAIN_BLOCKS (NNEG_TOT / 256)                // 3700 exactly

#define TBL_BYTES ((size_t)N_TOTAL * 128)           // 64 MB fp8 table
#define C8_OFF    TBL_BYTES
#define MPART_OFF (C8_OFF + (size_t)C_ROWS * 128)   // + 2,752,512
#define PPART_OFF (MPART_OFF + (size_t)MAIN_BLOCKS * 4)
#define WS_NEEDED (PPART_OFF + (size_t)BATCH * 4)   // ~67 MB

struct Pairs { unsigned char pi[N_PAIRS]; unsigned char pj[N_PAIRS]; };

constexpr Pairs make_pairs() {
    Pairs p{};
    int n = 0;
    for (int i = 0; i < P_NODES; ++i) {
        int jlo = (i - KNEG > 0) ? i - KNEG : 0;
        int jhi = (i + KNEG < P_NODES) ? i + KNEG : P_NODES;
        for (int j = jlo; j < jhi; ++j) { p.pi[n] = (unsigned char)i; p.pj[n] = (unsigned char)j; ++n; }
    }
    return p;
}

__constant__ Pairs PAIRS = make_pairs();

__device__ __forceinline__ float lsig(float x) {
    return -__logf(1.f + __expf(-x));   // dots are tiny; no overflow risk
}

__device__ __forceinline__ float dot4(float4 a, float4 b) {
    return fmaf(a.x, b.x, fmaf(a.y, b.y, fmaf(a.z, b.z, a.w * b.w)));
}

__device__ __forceinline__ int divk(int q) {        // q/5 exact for q < 2^18
    return (int)(((u32)q * 52429u) >> 18);
}

// ---- HW OCP-e4m3 codec (gfx950) ----
__device__ __forceinline__ u32 enc_pk4(float4 v) {
    int d = 0;
    d = __builtin_amdgcn_cvt_pk_fp8_f32(v.x, v.y, d, false);
    d = __builtin_amdgcn_cvt_pk_fp8_f32(v.z, v.w, d, true);
    return (u32)d;
}
__device__ __forceinline__ u32 enc_pk4v(f4v v) {
    int d = 0;
    d = __builtin_amdgcn_cvt_pk_fp8_f32(v.x, v.y, d, false);
    d = __builtin_amdgcn_cvt_pk_fp8_f32(v.z, v.w, d, true);
    return (u32)d;
}
__device__ __forceinline__ float dot_88(u32 a, u32 c) {         // fp8 . fp8
    vf2 la = __builtin_amdgcn_cvt_pk_f32_fp8((int)a, false);
    vf2 ha = __builtin_amdgcn_cvt_pk_f32_fp8((int)a, true);
    vf2 lc = __builtin_amdgcn_cvt_pk_f32_fp8((int)c, false);
    vf2 hc = __builtin_amdgcn_cvt_pk_f32_fp8((int)c, true);
    return fmaf(la.x, lc.x, fmaf(la.y, lc.y, fmaf(ha.x, hc.x, ha.y * hc.y)));
}

__global__ void kzero(float* __restrict__ out) {
    if (threadIdx.x == 0) out[0] = 0.f;
}

// ---- k_conv: stream f32 table -> fp8 table (64 MB). emb reads NONTEMPORAL
// (via ext_vector_type ptr — HIP_vector_type is rejected by the builtin) so the
// 256 MB sweep does not evict the just-written table from L3. ----
__global__ __launch_bounds__(256) void k_conv(const float* __restrict__ src,
                                              uint4* __restrict__ dst) {
    int t = blockIdx.x * 256 + threadIdx.x;
    const f4v* s4 = (const f4v*)src;
    f4v a = __builtin_nontemporal_load(s4 + 4 * (size_t)t + 0);
    f4v b = __builtin_nontemporal_load(s4 + 4 * (size_t)t + 1);
    f4v c = __builtin_nontemporal_load(s4 + 4 * (size_t)t + 2);
    f4v d = __builtin_nontemporal_load(s4 + 4 * (size_t)t + 3);
    dst[t] = make_uint4(enc_pk4v(a), enc_pk4v(b), enc_pk4v(c), enc_pk4v(d));
}

// ---- k_c8: fp8-encode the 21504 context rows (2.75 MB, cache-hot for k_main) ----
__global__ __launch_bounds__(256) void k_c8(
    const float* __restrict__ emb, const int* __restrict__ path, u32* __restrict__ C8)
{
    int t   = blockIdx.x * 256 + threadIdx.x;        // 688128 = 21504 * 32
    int cid = t >> 5, c = t & 31;
    int b   = cid / P_NODES;
    int i   = cid - b * P_NODES;
    int row = path[b * P_NODES + i];
    float4 v = ((const float4*)(emb + (size_t)row * DDIM))[c];
    C8[(size_t)cid * 32 + c] = enc_pk4(v);
}

// ---- k_pos: exact-f32 positive dots, one block per b; NO atomics (ppart[b]) ----
__global__ __launch_bounds__(256) void k_pos(
    const float* __restrict__ emb, const int* __restrict__ path,
    float* __restrict__ ppart)
{
    __shared__ float4 crow[P_NODES * 32];            // rotated
    __shared__ int pidx[P_NODES];
    __shared__ float wsum[4];
    const int b = blockIdx.x, t = threadIdx.x;
    if (t < P_NODES) pidx[t] = path[b * P_NODES + t];
    __syncthreads();
    for (int e = t; e < P_NODES * 32; e += 256) {
        int r = e >> 5, c = e & 31;
        crow[r * 32 + ((c + r) & 31)] = ((const float4*)(emb + (size_t)pidx[r] * DDIM))[c];
    }
    __syncthreads();
    float acc = 0.f;
    if (t < N_PAIRS) {
        const int ci = PAIRS.pi[t], cj = PAIRS.pj[t];
        const float4* cri = &crow[ci * 32];
        const float4* crj = &crow[cj * 32];
        float part = 0.f;
        #pragma unroll
        for (int s = 0; s < 32; ++s)
            part += dot4(cri[(s + ci) & 31], crj[(s + cj) & 31]);
        acc = lsig(part);
    }
    acc += __shfl_xor(acc, 32);
    acc += __shfl_xor(acc, 16);
    acc += __shfl_xor(acc, 8);
    acc += __shfl_xor(acc, 4);
    acc += __shfl_xor(acc, 2);
    acc += __shfl_xor(acc, 1);
    if ((t & 63) == 0) wsum[t >> 6] = acc;
    __syncthreads();
    if (t == 0) ppart[b] = wsum[0] + wsum[1] + wsum[2] + wsum[3];
}

// ---- k_main_flat: ONE TASK PER LANE (947200 lanes); NO atomics (mpart[blk]) ----
__global__ __launch_bounds__(256) void k_main_flat(
    const int*   __restrict__ neg,
    const uint4* __restrict__ tbl4,
    const uint4* __restrict__ C84,
    float*       __restrict__ mpart)
{
    __shared__ float wsum[4];
    const int q = blockIdx.x * 256 + threadIdx.x;    // < 947200 exactly
    const int p   = divk(q >> 10);                   // q / 5120
    const int rem = q - p * 5120;
    const int b   = divk(rem);                       // rem / 5
    const int cid = b * P_NODES + PAIRS.pi[p];

    const uint4* R = tbl4 + (size_t)neg[q] * 8;
    const uint4* C = C84  + (size_t)cid * 8;

    uint4 r0 = R[0], r1 = R[1], r2 = R[2], r3 = R[3];
    uint4 r4 = R[4], r5 = R[5], r6 = R[6], r7 = R[7];
    uint4 c0 = C[0], c1 = C[1], c2 = C[2], c3 = C[3];
    uint4 c4 = C[4], c5 = C[5], c6 = C[6], c7 = C[7];

    float part =
        dot_88(r0.x, c0.x) + dot_88(r0.y, c0.y) + dot_88(r0.z, c0.z) + dot_88(r0.w, c0.w) +
        dot_88(r1.x, c1.x) + dot_88(r1.y, c1.y) + dot_88(r1.z, c1.z) + dot_88(r1.w, c1.w) +
        dot_88(r2.x, c2.x) + dot_88(r2.y, c2.y) + dot_88(r2.z, c2.z) + dot_88(r2.w, c2.w) +
        dot_88(r3.x, c3.x) + dot_88(r3.y, c3.y) + dot_88(r3.z, c3.z) + dot_88(r3.w, c3.w) +
        dot_88(r4.x, c4.x) + dot_88(r4.y, c4.y) + dot_88(r4.z, c4.z) + dot_88(r4.w, c4.w) +
        dot_88(r5.x, c5.x) + dot_88(r5.y, c5.y) + dot_88(r5.z, c5.z) + dot_88(r5.w, c5.w) +
        dot_88(r6.x, c6.x) + dot_88(r6.y, c6.y) + dot_88(r6.z, c6.z) + dot_88(r6.w, c6.w) +
        dot_88(r7.x, c7.x) + dot_88(r7.y, c7.y) + dot_88(r7.z, c7.z) + dot_88(r7.w, c7.w);

    float acc = lsig(-part);

    acc += __shfl_xor(acc, 32);
    acc += __shfl_xor(acc, 16);
    acc += __shfl_xor(acc, 8);
    acc += __shfl_xor(acc, 4);
    acc += __shfl_xor(acc, 2);
    acc += __shfl_xor(acc, 1);
    if ((threadIdx.x & 63) == 0) wsum[threadIdx.x >> 6] = acc;
    __syncthreads();
    if (threadIdx.x == 0)
        mpart[blockIdx.x] = wsum[0] + wsum[1] + wsum[2] + wsum[3];
}

// ---- kfinal: sum 3700 + 1024 partials, write the scalar (overwrites out) ----
__global__ __launch_bounds__(256) void kfinal(
    const float* __restrict__ mpart, const float* __restrict__ ppart,
    float* __restrict__ out)
{
    __shared__ float wsum[4];
    const int t = threadIdx.x;
    float s = 0.f;
    for (int i = t; i < MAIN_BLOCKS; i += 256) s += mpart[i];
    for (int i = t; i < BATCH; i += 256) s += ppart[i];
    s += __shfl_xor(s, 32);
    s += __shfl_xor(s, 16);
    s += __shfl_xor(s, 8);
    s += __shfl_xor(s, 4);
    s += __shfl_xor(s, 2);
    s += __shfl_xor(s, 1);
    if ((t & 63) == 0) wsum[t >> 6] = s;
    __syncthreads();
    if (t == 0)
        out[0] = -(wsum[0] + wsum[1] + wsum[2] + wsum[3]) / (float)BATCH;
}

// ================= fallback (R6 kernel, verbatim) if ws is too small =================
#define NTASK_F (N_PAIRS + N_NEG)
#define HALF_T  (NTASK_F / 2)

__global__ __launch_bounds__(256) void mp2v_fallback(
    const float* __restrict__ emb, const int* __restrict__ path,
    const int* __restrict__ neg, float* __restrict__ out)
{
    __shared__ float4 crow[P_NODES * 32];
    __shared__ int    nidxf[N_NEG];
    __shared__ int    pidx[P_NODES];
    __shared__ unsigned char spi[N_PAIRS];
    __shared__ unsigned char spj[N_PAIRS];

    const int blk = blockIdx.x;
    const int b   = blk >> 1;
    const int q0  = (blk & 1) * HALF_T;
    const int q1  = q0 + HALF_T;
    const int t   = threadIdx.x;

    if (t < P_NODES) pidx[t] = path[b * P_NODES + t];
    if (t < N_PAIRS) { spi[t] = PAIRS.pi[t]; spj[t] = PAIRS.pj[t]; }
    for (int q = t; q < N_NEG; q += 256) {
        int p = divk(q);
        int k = q - p * KNEG;
        nidxf[q] = neg[(size_t)p * (BATCH * KNEG) + b * KNEG + k];
    }
    __syncthreads();
    for (int e = t; e < P_NODES * 32; e += 256) {
        int r = e >> 5, c = e & 31;
        float4 val = ((const float4*)(emb + (size_t)pidx[r] * DDIM))[c];
        crow[r * 32 + ((c + r) & 31)] = val;
    }
    __syncthreads();

    const int g = t >> 3, m = t & 7;
    const float4* emb4 = (const float4*)emb;
    float acc = 0.f;

    for (int base = q0; base < q1; base += 128) {
        float4 rv[4][4];
        int civ[4]; float sg[4]; bool vv[4];
        #pragma unroll
        for (int k = 0; k < 4; ++k) {
            int qq = base + g * 4 + k;
            bool v = qq < q1; vv[k] = v;
            int qc = v ? qq : q0;
            if (qc < N_NEG) {
                int p = divk(qc);
                civ[k] = spi[p]; sg[k] = -1.f;
                const float4* R = emb4 + (size_t)nidxf[qc] * 32;
                #pragma unroll
                for (int i = 0; i < 4; ++i) rv[k][i] = R[m + 8 * i];
            } else {
                int pp = qc - N_NEG;
                int cj = spj[pp];
                civ[k] = spi[pp]; sg[k] = 1.f;
                #pragma unroll
                for (int i = 0; i < 4; ++i) {
                    int c = m + 8 * i;
                    rv[k][i] = crow[cj * 32 + ((c + cj) & 31)];
                }
            }
        }
        #pragma unroll
        for (int k = 0; k < 4; ++k) {
            int ci = civ[k];
            float part = 0.f;
            #pragma unroll
            for (int i = 0; i < 4; ++i) {
                int c = m + 8 * i;
                part += dot4(rv[k][i], crow[ci * 32 + ((c + ci) & 31)]);
            }
            part += __shfl_xor(part, 1);
            part += __shfl_xor(part, 2);
            part += __shfl_xor(part, 4);
            if (vv[k]) acc += lsig(sg[k] * part);
        }
    }
    acc += __shfl_xor(acc, 32);
    acc += __shfl_xor(acc, 16);
    acc += __shfl_xor(acc, 8);
    acc += __shfl_xor(acc, 4);
    acc += __shfl_xor(acc, 2);
    acc += __shfl_xor(acc, 1);
    if ((t & 63) == 0) atomicAdd(out, acc * (-1.f / (8.f * (float)BATCH)));
}

extern "C" void kernel_launch(void* const* d_in, const int* in_sizes, int n_in,
                              void* d_out, int out_size, void* d_ws, size_t ws_size,
                              hipStream_t stream) {
    const float* emb  = (const float*)d_in[0];
    const int*   path = (const int*)d_in[1];
    const int*   neg  = (const int*)d_in[2];
    float*       out  = (float*)d_out;

    if (ws_size >= WS_NEEDED) {
        char*  ws    = (char*)d_ws;
        u32*   tbl   = (u32*)ws;
        u32*   C8    = (u32*)(ws + C8_OFF);
        float* mpart = (float*)(ws + MPART_OFF);
        float* ppart = (float*)(ws + PPART_OFF);

        k_pos<<<BATCH, 256, 0, stream>>>(emb, path, ppart);
        k_conv<<<CONV_BLOCKS, 256, 0, stream>>>(emb, (uint4*)tbl);
        k_c8 <<<(C_ROWS * 32) / 256, 256, 0, stream>>>(emb, path, C8);
        k_main_flat<<<MAIN_BLOCKS, 256, 0, stream>>>(neg, (const uint4*)tbl,
                                                     (const uint4*)C8, mpart);
        kfinal<<<1, 256, 0, stream>>>(mpart, ppart, out);
    } else {
        kzero<<<1, 64, 0, stream>>>(out);
        mp2v_fallback<<<BATCH * 2, 256, 0, stream>>>(emb, path, neg, out);
    }
}

// Round 19
// 101.629 us; speedup vs baseline: 1.2339x; 1.2339x over previous
//
#include <hip/hip_runtime.h>
#include <math.h>

typedef unsigned int u32;
typedef float vf2 __attribute__((ext_vector_type(2)));

#define N_TOTAL 500000
#define P_NODES 21
#define KNEG    5
#define DDIM    128
#define BATCH   1024
#define N_PAIRS 185
#define N_NEG   (N_PAIRS * KNEG)            // 925
#define NNEG_TOT (N_PAIRS * BATCH * KNEG)   // 947200
#define C_ROWS  (BATCH * P_NODES)           // 21504

#define CONV_BLOCKS ((N_TOTAL * DDIM / 16) / 256)   // 15625
#define MAIN_BLOCKS (NNEG_TOT / 256)                // 3700 exactly

#define TBL_BYTES ((size_t)N_TOTAL * 128)           // 64 MB fp8 table
#define C8_OFF    TBL_BYTES
#define MPART_OFF (C8_OFF + (size_t)C_ROWS * 128)   // + 2,752,512
#define PPART_OFF (MPART_OFF + (size_t)MAIN_BLOCKS * 4)
#define WS_NEEDED (PPART_OFF + (size_t)BATCH * 4)   // ~67 MB

struct Pairs { unsigned char pi[N_PAIRS]; unsigned char pj[N_PAIRS]; };

constexpr Pairs make_pairs() {
    Pairs p{};
    int n = 0;
    for (int i = 0; i < P_NODES; ++i) {
        int jlo = (i - KNEG > 0) ? i - KNEG : 0;
        int jhi = (i + KNEG < P_NODES) ? i + KNEG : P_NODES;
        for (int j = jlo; j < jhi; ++j) { p.pi[n] = (unsigned char)i; p.pj[n] = (unsigned char)j; ++n; }
    }
    return p;
}

__constant__ Pairs PAIRS = make_pairs();

__device__ __forceinline__ float lsig(float x) {
    return -__logf(1.f + __expf(-x));   // dots are tiny; no overflow risk
}

__device__ __forceinline__ float dot4(float4 a, float4 b) {
    return fmaf(a.x, b.x, fmaf(a.y, b.y, fmaf(a.z, b.z, a.w * b.w)));
}

__device__ __forceinline__ int divk(int q) {        // q/5 exact for q < 2^18
    return (int)(((u32)q * 52429u) >> 18);
}

// ---- HW OCP-e4m3 codec (gfx950) ----
__device__ __forceinline__ u32 enc_pk4(float4 v) {
    int d = 0;
    d = __builtin_amdgcn_cvt_pk_fp8_f32(v.x, v.y, d, false);
    d = __builtin_amdgcn_cvt_pk_fp8_f32(v.z, v.w, d, true);
    return (u32)d;
}
__device__ __forceinline__ float dot_88(u32 a, u32 c) {         // fp8 . fp8
    vf2 la = __builtin_amdgcn_cvt_pk_f32_fp8((int)a, false);
    vf2 ha = __builtin_amdgcn_cvt_pk_f32_fp8((int)a, true);
    vf2 lc = __builtin_amdgcn_cvt_pk_f32_fp8((int)c, false);
    vf2 hc = __builtin_amdgcn_cvt_pk_f32_fp8((int)c, true);
    return fmaf(la.x, lc.x, fmaf(la.y, lc.y, fmaf(ha.x, hc.x, ha.y * hc.y)));
}

__global__ void kzero(float* __restrict__ out) {
    if (threadIdx.x == 0) out[0] = 0.f;
}

// ---- k_conv: stream f32 table -> fp8 table (64 MB); plain cached loads
// (nt-loads measured SLOWER: R18 125.4 vs R16 101.9) ----
__global__ __launch_bounds__(256) void k_conv(const float4* __restrict__ src,
                                              uint4* __restrict__ dst) {
    int t = blockIdx.x * 256 + threadIdx.x;
    float4 a = src[4 * (size_t)t + 0];
    float4 b = src[4 * (size_t)t + 1];
    float4 c = src[4 * (size_t)t + 2];
    float4 d = src[4 * (size_t)t + 3];
    dst[t] = make_uint4(enc_pk4(a), enc_pk4(b), enc_pk4(c), enc_pk4(d));
}

// ---- k_c8: fp8-encode the 21504 context rows (2.75 MB, cache-hot for k_main) ----
__global__ __launch_bounds__(256) void k_c8(
    const float* __restrict__ emb, const int* __restrict__ path, u32* __restrict__ C8)
{
    int t   = blockIdx.x * 256 + threadIdx.x;        // 688128 = 21504 * 32
    int cid = t >> 5, c = t & 31;
    int b   = cid / P_NODES;
    int i   = cid - b * P_NODES;
    int row = path[b * P_NODES + i];
    float4 v = ((const float4*)(emb + (size_t)row * DDIM))[c];
    C8[(size_t)cid * 32 + c] = enc_pk4(v);
}

// ---- k_pos: exact-f32 positive dots, one block per b; NO atomics (ppart[b]) ----
__global__ __launch_bounds__(256) void k_pos(
    const float* __restrict__ emb, const int* __restrict__ path,
    float* __restrict__ ppart)
{
    __shared__ float4 crow[P_NODES * 32];            // rotated
    __shared__ int pidx[P_NODES];
    __shared__ float wsum[4];
    const int b = blockIdx.x, t = threadIdx.x;
    if (t < P_NODES) pidx[t] = path[b * P_NODES + t];
    __syncthreads();
    for (int e = t; e < P_NODES * 32; e += 256) {
        int r = e >> 5, c = e & 31;
        crow[r * 32 + ((c + r) & 31)] = ((const float4*)(emb + (size_t)pidx[r] * DDIM))[c];
    }
    __syncthreads();
    float acc = 0.f;
    if (t < N_PAIRS) {
        const int ci = PAIRS.pi[t], cj = PAIRS.pj[t];
        const float4* cri = &crow[ci * 32];
        const float4* crj = &crow[cj * 32];
        float part = 0.f;
        #pragma unroll
        for (int s = 0; s < 32; ++s)
            part += dot4(cri[(s + ci) & 31], crj[(s + cj) & 31]);
        acc = lsig(part);
    }
    acc += __shfl_xor(acc, 32);
    acc += __shfl_xor(acc, 16);
    acc += __shfl_xor(acc, 8);
    acc += __shfl_xor(acc, 4);
    acc += __shfl_xor(acc, 2);
    acc += __shfl_xor(acc, 1);
    if ((t & 63) == 0) wsum[t >> 6] = acc;
    __syncthreads();
    if (t == 0) ppart[b] = wsum[0] + wsum[1] + wsum[2] + wsum[3];
}

// ---- k_main_flat: ONE TASK PER LANE (947200 lanes); NO atomics (mpart[blk]) ----
__global__ __launch_bounds__(256) void k_main_flat(
    const int*   __restrict__ neg,
    const uint4* __restrict__ tbl4,
    const uint4* __restrict__ C84,
    float*       __restrict__ mpart)
{
    __shared__ float wsum[4];
    const int q = blockIdx.x * 256 + threadIdx.x;    // < 947200 exactly
    const int p   = divk(q >> 10);                   // q / 5120
    const int rem = q - p * 5120;
    const int b   = divk(rem);                       // rem / 5
    const int cid = b * P_NODES + PAIRS.pi[p];

    const uint4* R = tbl4 + (size_t)neg[q] * 8;
    const uint4* C = C84  + (size_t)cid * 8;

    uint4 r0 = R[0], r1 = R[1], r2 = R[2], r3 = R[3];
    uint4 r4 = R[4], r5 = R[5], r6 = R[6], r7 = R[7];
    uint4 c0 = C[0], c1 = C[1], c2 = C[2], c3 = C[3];
    uint4 c4 = C[4], c5 = C[5], c6 = C[6], c7 = C[7];

    float part =
        dot_88(r0.x, c0.x) + dot_88(r0.y, c0.y) + dot_88(r0.z, c0.z) + dot_88(r0.w, c0.w) +
        dot_88(r1.x, c1.x) + dot_88(r1.y, c1.y) + dot_88(r1.z, c1.z) + dot_88(r1.w, c1.w) +
        dot_88(r2.x, c2.x) + dot_88(r2.y, c2.y) + dot_88(r2.z, c2.z) + dot_88(r2.w, c2.w) +
        dot_88(r3.x, c3.x) + dot_88(r3.y, c3.y) + dot_88(r3.z, c3.z) + dot_88(r3.w, c3.w) +
        dot_88(r4.x, c4.x) + dot_88(r4.y, c4.y) + dot_88(r4.z, c4.z) + dot_88(r4.w, c4.w) +
        dot_88(r5.x, c5.x) + dot_88(r5.y, c5.y) + dot_88(r5.z, c5.z) + dot_88(r5.w, c5.w) +
        dot_88(r6.x, c6.x) + dot_88(r6.y, c6.y) + dot_88(r6.z, c6.z) + dot_88(r6.w, c6.w) +
        dot_88(r7.x, c7.x) + dot_88(r7.y, c7.y) + dot_88(r7.z, c7.z) + dot_88(r7.w, c7.w);

    float acc = lsig(-part);

    acc += __shfl_xor(acc, 32);
    acc += __shfl_xor(acc, 16);
    acc += __shfl_xor(acc, 8);
    acc += __shfl_xor(acc, 4);
    acc += __shfl_xor(acc, 2);
    acc += __shfl_xor(acc, 1);
    if ((threadIdx.x & 63) == 0) wsum[threadIdx.x >> 6] = acc;
    __syncthreads();
    if (threadIdx.x == 0)
        mpart[blockIdx.x] = wsum[0] + wsum[1] + wsum[2] + wsum[3];
}

// ---- kfinal: sum 3700 + 1024 partials, write the scalar (overwrites out) ----
__global__ __launch_bounds__(256) void kfinal(
    const float* __restrict__ mpart, const float* __restrict__ ppart,
    float* __restrict__ out)
{
    __shared__ float wsum[4];
    const int t = threadIdx.x;
    float s = 0.f;
    for (int i = t; i < MAIN_BLOCKS; i += 256) s += mpart[i];
    for (int i = t; i < BATCH; i += 256) s += ppart[i];
    s += __shfl_xor(s, 32);
    s += __shfl_xor(s, 16);
    s += __shfl_xor(s, 8);
    s += __shfl_xor(s, 4);
    s += __shfl_xor(s, 2);
    s += __shfl_xor(s, 1);
    if ((t & 63) == 0) wsum[t >> 6] = s;
    __syncthreads();
    if (t == 0)
        out[0] = -(wsum[0] + wsum[1] + wsum[2] + wsum[3]) / (float)BATCH;
}

// ================= fallback (R6 kernel, verbatim) if ws is too small =================
#define NTASK_F (N_PAIRS + N_NEG)
#define HALF_T  (NTASK_F / 2)

__global__ __launch_bounds__(256) void mp2v_fallback(
    const float* __restrict__ emb, const int* __restrict__ path,
    const int* __restrict__ neg, float* __restrict__ out)
{
    __shared__ float4 crow[P_NODES * 32];
    __shared__ int    nidxf[N_NEG];
    __shared__ int    pidx[P_NODES];
    __shared__ unsigned char spi[N_PAIRS];
    __shared__ unsigned char spj[N_PAIRS];

    const int blk = blockIdx.x;
    const int b   = blk >> 1;
    const int q0  = (blk & 1) * HALF_T;
    const int q1  = q0 + HALF_T;
    const int t   = threadIdx.x;

    if (t < P_NODES) pidx[t] = path[b * P_NODES + t];
    if (t < N_PAIRS) { spi[t] = PAIRS.pi[t]; spj[t] = PAIRS.pj[t]; }
    for (int q = t; q < N_NEG; q += 256) {
        int p = divk(q);
        int k = q - p * KNEG;
        nidxf[q] = neg[(size_t)p * (BATCH * KNEG) + b * KNEG + k];
    }
    __syncthreads();
    for (int e = t; e < P_NODES * 32; e += 256) {
        int r = e >> 5, c = e & 31;
        float4 val = ((const float4*)(emb + (size_t)pidx[r] * DDIM))[c];
        crow[r * 32 + ((c + r) & 31)] = val;
    }
    __syncthreads();

    const int g = t >> 3, m = t & 7;
    const float4* emb4 = (const float4*)emb;
    float acc = 0.f;

    for (int base = q0; base < q1; base += 128) {
        float4 rv[4][4];
        int civ[4]; float sg[4]; bool vv[4];
        #pragma unroll
        for (int k = 0; k < 4; ++k) {
            int qq = base + g * 4 + k;
            bool v = qq < q1; vv[k] = v;
            int qc = v ? qq : q0;
            if (qc < N_NEG) {
                int p = divk(qc);
                civ[k] = spi[p]; sg[k] = -1.f;
                const float4* R = emb4 + (size_t)nidxf[qc] * 32;
                #pragma unroll
                for (int i = 0; i < 4; ++i) rv[k][i] = R[m + 8 * i];
            } else {
                int pp = qc - N_NEG;
                int cj = spj[pp];
                civ[k] = spi[pp]; sg[k] = 1.f;
                #pragma unroll
                for (int i = 0; i < 4; ++i) {
                    int c = m + 8 * i;
                    rv[k][i] = crow[cj * 32 + ((c + cj) & 31)];
                }
            }
        }
        #pragma unroll
        for (int k = 0; k < 4; ++k) {
            int ci = civ[k];
            float part = 0.f;
            #pragma unroll
            for (int i = 0; i < 4; ++i) {
                int c = m + 8 * i;
                part += dot4(rv[k][i], crow[ci * 32 + ((c + ci) & 31)]);
            }
            part += __shfl_xor(part, 1);
            part += __shfl_xor(part, 2);
            part += __shfl_xor(part, 4);
            if (vv[k]) acc += lsig(sg[k] * part);
        }
    }
    acc += __shfl_xor(acc, 32);
    acc += __shfl_xor(acc, 16);
    acc += __shfl_xor(acc, 8);
    acc += __shfl_xor(acc, 4);
    acc += __shfl_xor(acc, 2);
    acc += __shfl_xor(acc, 1);
    if ((t & 63) == 0) atomicAdd(out, acc * (-1.f / (8.f * (float)BATCH)));
}

extern "C" void kernel_launch(void* const* d_in, const int* in_sizes, int n_in,
                              void* d_out, int out_size, void* d_ws, size_t ws_size,
                              hipStream_t stream) {
    const float* emb  = (const float*)d_in[0];
    const int*   path = (const int*)d_in[1];
    const int*   neg  = (const int*)d_in[2];
    float*       out  = (float*)d_out;

    if (ws_size >= WS_NEEDED) {
        char*  ws    = (char*)d_ws;
        u32*   tbl   = (u32*)ws;
        u32*   C8    = (u32*)(ws + C8_OFF);
        float* mpart = (float*)(ws + MPART_OFF);
        float* ppart = (float*)(ws + PPART_OFF);

        k_pos<<<BATCH, 256, 0, stream>>>(emb, path, ppart);
        k_conv<<<CONV_BLOCKS, 256, 0, stream>>>((const float4*)emb, (uint4*)tbl);
        k_c8 <<<(C_ROWS * 32) / 256, 256, 0, stream>>>(emb, path, C8);
        k_main_flat<<<MAIN_BLOCKS, 256, 0, stream>>>(neg, (const uint4*)tbl,
                                                     (const uint4*)C8, mpart);
        kfinal<<<1, 256, 0, stream>>>(mpart, ppart, out);
    } else {
        kzero<<<1, 64, 0, stream>>>(out);
        mp2v_fallback<<<BATCH * 2, 256, 0, stream>>>(emb, path, neg, out);
    }
}